// Round 8
// baseline (243.441 us; speedup 1.0000x reference)
//
#include <hip/hip_runtime.h>
#include <math.h>

#define SHEET 160
#define LTOT (SHEET*SHEET)          // 25600
#define F_AFF 450
#define F_LAT 625
#define N_ITERS 10
#define IN_HW 174                   // SHEET + AFF_K - 1
#define HOMEO 0.02f
#define PI_D 3.14159265358979323846

// ---- lateral tile geometry: 4 rows x 8 cols of locations per block ----
#define BH 4
#define BW 8
#define BLK 512                     // 8 waves, each handles 4 locations
#define TCOLS (SHEET/BW)            // 20
#define GRID_L ((SHEET/BH)*TCOLS)   // 40*20 = 800 blocks (~3.1/CU)
#define EH 52                       // BH + 48 E-field rows
#define EWH 29                      // (BW+48)/2 + 1 pad (parity-half width)
#define EP_HALF (EH*EWH)            // 1508
#define EP_N (2*EP_HALF)            // 3016
#define LW 61                       // BW+52=60 cols, padded to 61
#define LH 56                       // BH + 52
#define LT_N (LH*LW)                // 3416

// afferent / pack geometry: wave-per-location
#define AWPB 8
#define ABLK (AWPB*64)
#define ANBLK (LTOT/AWPB)           // 3200

// ---- workspace layout (float offsets) ----
#define WS_SRE    0                 // 32 (25 used)
#define WS_LATTAB 32                // float2[640] {lri, off}
#define WS_AFFTAB 1312              // float2[512] {env, off}
#define WS_AFF    2336
#define WS_B0     (WS_AFF + LTOT)
#define WS_B1     (WS_B0  + LTOT)
#define WS_LM     (WS_B1  + LTOT)
#define WS_WQ     (WS_LM  + LTOT + 64)   // 25600*320 u32 = 32.8 MB

__device__ __forceinline__ float wred(float v) {
    #pragma unroll
    for (int m = 32; m > 0; m >>= 1) v += __shfl_xor(v, m, 64);
    return v;
}

__device__ __forceinline__ unsigned f2bf(float f) {   // RNE float->bf16 bits
    unsigned u = __float_as_uint(f);
    return (u + 0x7FFFu + ((u >> 16) & 1u)) >> 16;
}

// ---------------- init: constant tables + scalar-output zero ----------------
__global__ __launch_bounds__(1024) void k_init(float* __restrict__ ws,
                                               float* __restrict__ out) {
    __shared__ float red[1024];
    const int t = threadIdx.x;

    if (t == 0) out[2 * LTOT] = 0.f;   // k_hebb atomicAdds into this

    float sre_raw = 0.f;
    if (t < 25) {
        int u = t / 5, v = t % 5;
        double d = sqrt((double)((u-2)*(u-2) + (v-2)*(v-2)));
        if (d < 2.5) { double cv = cos(fmin(d/5.0, 1.0) * PI_D * 0.5); sre_raw = (float)(cv*cv); }
    }

    float lri_raw = 0.f;
    const int dy = t / 25, dx = t % 25;
    if (t < 625) {
        double d = sqrt((double)((dy-12)*(dy-12) + (dx-12)*(dx-12)));
        double base = 0.0, inh = 0.0;
        if (d < 12.5) { double cv = cos(fmin(d/25.0, 1.0) * PI_D * 0.5); base = cv*cv; }
        if (d < 1.25) { double cv = cos(fmin(d/2.5,  1.0) * PI_D * 0.5); inh  = cv*cv; }
        lri_raw = (float)(base * (1.0 - inh));
    }

    red[t] = lri_raw;
    __syncthreads();
    #pragma unroll
    for (int s = 512; s > 0; s >>= 1) {
        if (t < s) red[t] = fmaxf(red[t], red[t + s]);
        __syncthreads();
    }
    const float lri_max = red[0];
    __syncthreads();

    red[t] = sre_raw;
    __syncthreads();
    #pragma unroll
    for (int s = 512; s > 0; s >>= 1) {
        if (t < s) red[t] += red[t + s];
        __syncthreads();
    }
    const float sre_sum = red[0];

    if (t < 32) ws[WS_SRE + t] = (t < 25) ? sre_raw / sre_sum : 0.f;

    // lateral table: {lri_norm, gather offset dy*(2*EWH)+dx}; lri=0 for t>=625
    if (t < 640) {
        float lv = (t < 625) ? lri_raw / lri_max : 0.f;
        int  off = (t < 625) ? (dy * (2*EWH) + dx) : 0;
        ((float2*)(ws + WS_LATTAB))[t] = make_float2(lv, __int_as_float(off));
    }

    // afferent table: {env, x offset}
    if (t < 512) {
        float ev = 0.f; int off = 0;
        if (t < 450) {
            int c  = t / 225, rr = t % 225;
            int kh = rr / 15, kw = rr % 15;
            double d = sqrt((double)((kh-7)*(kh-7) + (kw-7)*(kw-7)));
            if (d < 7.5) { double cv = cos(fmin(d/15.0, 1.0) * PI_D * 0.5); ev = (float)(cv*cv); }
            off = c * (IN_HW*IN_HW) + kh * IN_HW + kw;
        }
        ((float2*)(ws + WS_AFFTAB))[t] = make_float2(ev, __int_as_float(off));
    }
}

// ---------------- fused afferent pass + weight pack (float4-staged streams) ----------------
// blocks [0, ANBLK): afferent (rfs). blocks [ANBLK, 2*ANBLK): latw pack.
__global__ __launch_bounds__(ABLK) void k_pre(const float* __restrict__ x,
                                              const float* __restrict__ rfs,
                                              const float* __restrict__ latw,
                                              const float* __restrict__ ada,
                                              float* __restrict__ out_rawaff,
                                              float* __restrict__ ws,
                                              unsigned* __restrict__ wq) {
    __shared__ __align__(16) float S[5016];
    const int w = threadIdx.x >> 6, lane = threadIdx.x & 63;

    if (blockIdx.x < ANBLK) {
        // ---- stage 8 rfs rows (8*450*4B = 14400B, 16B-aligned per block) ----
        const float4* src4 = (const float4*)(rfs + (size_t)blockIdx.x * (8*F_AFF));
        for (int idx = threadIdx.x; idx < 900; idx += ABLK) ((float4*)S)[idx] = src4[idx];
        __syncthreads();

        const float2* tab = (const float2*)(ws + WS_AFFTAB);
        const int l = blockIdx.x * AWPB + w;
        const int i = l / SHEET, j = l % SHEET;
        const int xbase = i * IN_HW + j;

        float dot = 0.f, sum = 0.f;
        #pragma unroll
        for (int it = 0; it < 8; ++it) {
            int f = it * 64 + lane;
            float2 tb = tab[f];
            float rv = S[w * F_AFF + f];           // may over-read staged area; S is padded
            if (f >= F_AFF) rv = 0.f;
            float xv = x[xbase + __float_as_int(tb.y)];
            dot = fmaf(xv * tb.x, rv, dot);
            sum += rv;
        }
        dot = wred(dot);
        sum = wred(sum);
        if (lane == 0) {
            float a = dot / sum;
            out_rawaff[l] = 45.0f * a;                 // raw_aff
            float aff = a - ada[l];
            ws[WS_AFF + l] = aff;
            ws[WS_B0  + l] = fmaxf(aff, 0.f);          // lat_0 = relu(aff)
            ws[WS_LM  + l] = 0.f;
        }
    } else {
        // ---- stage 8 latw rows (8*625*4B = 20000B, 16B-aligned per block) ----
        const float4* src4 = (const float4*)(latw + (size_t)(blockIdx.x - ANBLK) * (8*F_LAT));
        for (int idx = threadIdx.x; idx < 1250; idx += ABLK) ((float4*)S)[idx] = src4[idx];
        __syncthreads();

        const int l = (blockIdx.x - ANBLK) * AWPB + w;
        const float2* tab = (const float2*)(ws + WS_LATTAB);

        float tmp[10], sum = 0.f;
        #pragma unroll
        for (int it = 0; it < 10; ++it) {
            int f = it * 64 + lane;
            float lri = tab[f].x;                      // 0 for f >= 625
            float wv = S[w * F_LAT + f];
            if (f >= F_LAT) wv = 0.f;
            sum += wv;
            tmp[it] = wv * lri;
        }
        sum = wred(sum);
        const float inv = 1.0f / sum;

        unsigned* dst = wq + (size_t)l * 320;
        #pragma unroll
        for (int k = 0; k < 5; ++k) {
            unsigned lo = f2bf(tmp[k]     * inv);
            unsigned hi = f2bf(tmp[k + 5] * inv);
            dst[k * 64 + lane] = lo | (hi << 16);
        }
    }
}

// ---------------- lateral iteration: prefetched weights + fused conv + 625-dot ----------------
__global__ __launch_bounds__(BLK, 4) void k_lat(const unsigned* __restrict__ wq,
                                                float* __restrict__ ws,
                                                const float* __restrict__ lsrc,
                                                float* __restrict__ lat_out) {
    __shared__ float Lt[LT_N];
    __shared__ float Ep[EP_N];
    const int b  = blockIdx.x;
    const int i0 = (b / TCOLS) * BH;
    const int j0 = (b % TCOLS) * BW;
    const int tid = threadIdx.x;
    const int w = tid >> 6, lane = tid & 63;

    // gather-offset table (per-lane registers)
    const float2* tab = (const float2*)(ws + WS_LATTAB);
    int off_reg[10];
    #pragma unroll
    for (int it = 0; it < 10; ++it) off_reg[it] = __float_as_int(tab[it * 64 + lane].y);

    // ---- prefetch this wave's 4 locations' packed weights (hides L2 latency under conv) ----
    unsigned wp[4][5];
    #pragma unroll
    for (int s = 0; s < 4; ++s) {
        int li = w * 4 + s;
        int r  = li >> 3, cc = li & 7;
        const unsigned* row = wq + (size_t)((i0 + r) * SHEET + (j0 + cc)) * 320;
        #pragma unroll
        for (int k = 0; k < 5; ++k) wp[s][k] = row[k * 64 + lane];
    }

    // sre in registers (uniform)
    float sreg[25];
    #pragma unroll
    for (int q = 0; q < 25; ++q) sreg[q] = ws[WS_SRE + q];

    // ---- stage L tile (pad = HOMEO), 56 x 60 (width padded to 61) ----
    for (int idx = tid; idx < LT_N; idx += BLK) {
        int r = idx / LW, c = idx - r * LW;
        int y  = i0 + r - 26;
        int xx = j0 + c - 26;
        float v = HOMEO;
        if (c < 60 && (unsigned)y < SHEET && (unsigned)xx < SHEET) v = lsrc[y*SHEET + xx];
        Lt[idx] = v;
    }
    __syncthreads();

    // ---- 5x5 conv -> E field (4-wide register blocked, parity-split store) ----
    for (int qi = tid; qi < EH * 14; qi += BLK) {
        int y = qi / 14, q = qi - y * 14;
        int x0 = q * 4;
        float a0 = 0.f, a1 = 0.f, a2 = 0.f, a3 = 0.f;
        #pragma unroll
        for (int u = 0; u < 5; ++u) {
            const float* row = &Lt[(y + u) * LW + x0];
            float ra[8];
            #pragma unroll
            for (int v = 0; v < 8; ++v) ra[v] = row[v];
            #pragma unroll
            for (int v = 0; v < 5; ++v) {
                float s = sreg[u * 5 + v];
                a0 = fmaf(ra[v],     s, a0);
                a1 = fmaf(ra[v + 1], s, a1);
                a2 = fmaf(ra[v + 2], s, a2);
                a3 = fmaf(ra[v + 3], s, a3);
            }
        }
        int yg = i0 - 24 + y;
        bool yok = (unsigned)yg < SHEET;
        int xg = j0 - 24 + x0;
        float v0 = (yok && (unsigned)(xg    ) < SHEET) ? a0 : HOMEO;
        float v1 = (yok && (unsigned)(xg + 1) < SHEET) ? a1 : HOMEO;
        float v2 = (yok && (unsigned)(xg + 2) < SHEET) ? a2 : HOMEO;
        float v3 = (yok && (unsigned)(xg + 3) < SHEET) ? a3 : HOMEO;
        int c0 = y * EWH + 2 * q;
        Ep[c0]               = v0;
        Ep[EP_HALF + c0]     = v1;
        Ep[c0 + 1]           = v2;
        Ep[EP_HALF + c0 + 1] = v3;
    }
    __syncthreads();

    // ---- per-location 625-dot from register-resident bf16 weights ----
    #pragma unroll
    for (int s = 0; s < 4; ++s) {
        int li = w * 4 + s;
        int r  = li >> 3, cc = li & 7;
        int l  = (i0 + r) * SHEET + (j0 + cc);
        int gbase = (cc & 1) * EP_HALF + r * EWH + (cc >> 1);

        float acc = 0.f;
        #pragma unroll
        for (int k = 0; k < 5; ++k) {
            unsigned p = wp[s][k];
            float e0 = Ep[gbase + off_reg[k]];
            float e1 = Ep[gbase + off_reg[k + 5]];
            acc = fmaf(e0, __uint_as_float(p << 16),         acc);
            acc = fmaf(e1, __uint_as_float(p & 0xffff0000u), acc);
        }
        acc = wred(acc);

        if (lane == 0) {
            float ec = Ep[gbase + 24*EWH + 12];
            float v = ec * 0.45f - acc * 0.55f + ws[WS_AFF + l];
            v = tanhf(fmaxf(v, 0.f));
            lat_out[l] = v;
            ws[WS_LM + l] += v;
        }
    }
}

// ---------------- hebbian correlation (atomic partial sum) ----------------
__global__ __launch_bounds__(BLK, 4) void k_hebb(const unsigned* __restrict__ wq,
                                                 float* __restrict__ ws,
                                                 float* __restrict__ out_scalar) {
    __shared__ float LMp[EP_N];
    __shared__ float part[8];
    const int b  = blockIdx.x;
    const int i0 = (b / TCOLS) * BH;
    const int j0 = (b % TCOLS) * BW;
    const int tid = threadIdx.x;
    const int w = tid >> 6, lane = tid & 63;
    const float* lm = ws + WS_LM;

    const float2* tab = (const float2*)(ws + WS_LATTAB);
    int off_reg[10];
    #pragma unroll
    for (int it = 0; it < 10; ++it) off_reg[it] = __float_as_int(tab[it * 64 + lane].y);

    unsigned wp[4][5];
    #pragma unroll
    for (int s = 0; s < 4; ++s) {
        int li = w * 4 + s;
        int r  = li >> 3, cc = li & 7;
        const unsigned* row = wq + (size_t)((i0 + r) * SHEET + (j0 + cc)) * 320;
        #pragma unroll
        for (int k = 0; k < 5; ++k) wp[s][k] = row[k * 64 + lane];
    }

    for (int idx = tid; idx < EP_N; idx += BLK) {
        int p   = idx / EP_HALF;
        int rem = idx - p * EP_HALF;
        int y   = rem / EWH;
        int col = rem - y * EWH;
        int yg = i0 - 24 + y;
        int xg = j0 - 24 + 2 * col + p;
        float v = HOMEO;
        if ((unsigned)yg < SHEET && (unsigned)xg < SHEET) v = lm[yg*SHEET + xg] * 0.1f;
        LMp[idx] = v;
    }
    __syncthreads();

    float wacc = 0.f;
    #pragma unroll
    for (int s = 0; s < 4; ++s) {
        int li = w * 4 + s;
        int r  = li >> 3, cc = li & 7;
        int gbase = (cc & 1) * EP_HALF + r * EWH + (cc >> 1);

        float acc = 0.f;
        #pragma unroll
        for (int k = 0; k < 5; ++k) {
            unsigned p = wp[s][k];
            float e0 = LMp[gbase + off_reg[k]];
            float e1 = LMp[gbase + off_reg[k + 5]];
            acc = fmaf(e0, __uint_as_float(p << 16),         acc);
            acc = fmaf(e1, __uint_as_float(p & 0xffff0000u), acc);
        }
        acc = wred(acc);
        if (lane == 0) {
            float lmv = LMp[gbase + 24*EWH + 12];      // lat_mean[l] * 0.1
            wacc += lmv * 62.5f * acc;
        }
    }
    if (lane == 0) part[w] = wacc;
    __syncthreads();
    if (tid == 0) {
        float s = 0.f;
        #pragma unroll
        for (int q = 0; q < 8; ++q) s += part[q];
        atomicAdd(out_scalar, s);
    }
}

extern "C" void kernel_launch(void* const* d_in, const int* in_sizes, int n_in,
                              void* d_out, int out_size, void* d_ws, size_t ws_size,
                              hipStream_t stream) {
    const float* x    = (const float*)d_in[0];
    const float* rfs  = (const float*)d_in[1];
    const float* latw = (const float*)d_in[2];
    const float* ada  = (const float*)d_in[3];
    float* out = (float*)d_out;
    float* ws  = (float*)d_ws;
    unsigned* wq = (unsigned*)(ws + WS_WQ);

    k_init<<<1, 1024, 0, stream>>>(ws, out);
    k_pre<<<2 * ANBLK, ABLK, 0, stream>>>(x, rfs, latw, ada, out, ws, wq);

    for (int t = 0; t < N_ITERS; ++t) {
        const float* src = ws + ((t & 1) ? WS_B1 : WS_B0);
        float* dst = (t == N_ITERS - 1) ? (out + LTOT)
                                        : (ws + ((t & 1) ? WS_B0 : WS_B1));
        k_lat<<<GRID_L, BLK, 0, stream>>>(wq, ws, src, dst);
    }

    k_hebb<<<GRID_L, BLK, 0, stream>>>(wq, ws, out + 2 * LTOT);
}

// Round 9
// 201.486 us; speedup vs baseline: 1.2082x; 1.2082x over previous
//
#include <hip/hip_runtime.h>
#include <math.h>

#define SHEET 160
#define LTOT (SHEET*SHEET)          // 25600
#define F_AFF 450
#define F_LAT 625
#define N_ITERS 10
#define IN_HW 174                   // SHEET + AFF_K - 1
#define HOMEO 0.02f
#define PI_D 3.14159265358979323846

// ---- lateral tile geometry: 5 rows x 10 cols of locations per block ----
#define BH 5
#define BW 10
#define BLK 320                     // 5 waves, each handles one row (10 locations)
#define TCOLS (SHEET/BW)            // 16
#define GRID_L ((SHEET/BH)*TCOLS)   // 32*16 = 512 blocks = exactly 2/CU
#define EH 53                       // BH + 48 E-field rows
#define EWH 30                      // 58/2 = 29 data cols per parity half, +1 pad
#define EP_HALF (EH*EWH)            // 1590
#define EP_N (2*EP_HALF)            // 3180
#define LW 63                       // 62 data cols padded to 63
#define LH 57                       // BH + 52
#define LT_N (LH*LW)                // 3591

// pre-pass geometry: wave-per-location (afferent + pack fused)
#define AWPB 8
#define ABLK (AWPB*64)
#define ANBLK (LTOT/AWPB)           // 3200

// ---- workspace layout (float offsets) ----
#define WS_SRE    0                 // 32 (25 used)
#define WS_LATTAB 32                // float2[640] {lri, off}
#define WS_AFFTAB 1312              // float2[512] {env, off}
#define WS_AFF    2336
#define WS_B0     (WS_AFF + LTOT)
#define WS_B1     (WS_B0  + LTOT)
#define WS_LM     (WS_B1  + LTOT)
#define WS_PART   (WS_LM  + LTOT)   // GRID_L floats
#define WS_WQ     (WS_PART + 512)   // 25600*320 u32 = 32.8 MB

__device__ __forceinline__ float wred(float v) {
    #pragma unroll
    for (int m = 32; m > 0; m >>= 1) v += __shfl_xor(v, m, 64);
    return v;
}

__device__ __forceinline__ unsigned f2bf(float f) {   // RNE float->bf16 bits
    unsigned u = __float_as_uint(f);
    return (u + 0x7FFFu + ((u >> 16) & 1u)) >> 16;
}

// ---------------- init: constant tables ----------------
__global__ __launch_bounds__(1024) void k_init(float* __restrict__ ws) {
    __shared__ float red[1024];
    const int t = threadIdx.x;

    float sre_raw = 0.f;
    if (t < 25) {
        int u = t / 5, v = t % 5;
        double d = sqrt((double)((u-2)*(u-2) + (v-2)*(v-2)));
        if (d < 2.5) { double cv = cos(fmin(d/5.0, 1.0) * PI_D * 0.5); sre_raw = (float)(cv*cv); }
    }

    float lri_raw = 0.f;
    const int dy = t / 25, dx = t % 25;
    if (t < 625) {
        double d = sqrt((double)((dy-12)*(dy-12) + (dx-12)*(dx-12)));
        double base = 0.0, inh = 0.0;
        if (d < 12.5) { double cv = cos(fmin(d/25.0, 1.0) * PI_D * 0.5); base = cv*cv; }
        if (d < 1.25) { double cv = cos(fmin(d/2.5,  1.0) * PI_D * 0.5); inh  = cv*cv; }
        lri_raw = (float)(base * (1.0 - inh));
    }

    red[t] = lri_raw;
    __syncthreads();
    #pragma unroll
    for (int s = 512; s > 0; s >>= 1) {
        if (t < s) red[t] = fmaxf(red[t], red[t + s]);
        __syncthreads();
    }
    const float lri_max = red[0];
    __syncthreads();

    red[t] = sre_raw;
    __syncthreads();
    #pragma unroll
    for (int s = 512; s > 0; s >>= 1) {
        if (t < s) red[t] += red[t + s];
        __syncthreads();
    }
    const float sre_sum = red[0];

    if (t < 32) ws[WS_SRE + t] = (t < 25) ? sre_raw / sre_sum : 0.f;

    // lateral table: {lri_norm, gather offset dy*(2*EWH)+dx}; lri=0 for t>=625
    if (t < 640) {
        float lv = (t < 625) ? lri_raw / lri_max : 0.f;
        int  off = (t < 625) ? (dy * (2*EWH) + dx) : 0;
        ((float2*)(ws + WS_LATTAB))[t] = make_float2(lv, __int_as_float(off));
    }

    // afferent table: {env, x offset}
    if (t < 512) {
        float ev = 0.f; int off = 0;
        if (t < 450) {
            int c  = t / 225, rr = t % 225;
            int kh = rr / 15, kw = rr % 15;
            double d = sqrt((double)((kh-7)*(kh-7) + (kw-7)*(kw-7)));
            if (d < 7.5) { double cv = cos(fmin(d/15.0, 1.0) * PI_D * 0.5); ev = (float)(cv*cv); }
            off = c * (IN_HW*IN_HW) + kh * IN_HW + kw;
        }
        ((float2*)(ws + WS_AFFTAB))[t] = make_float2(ev, __int_as_float(off));
    }
}

// ---------------- fused afferent + pack: one wave = one location, both streams ----------------
__global__ __launch_bounds__(ABLK) void k_pre(const float* __restrict__ x,
                                              const float* __restrict__ rfs,
                                              const float* __restrict__ latw,
                                              const float* __restrict__ ada,
                                              float* __restrict__ out_rawaff,
                                              float* __restrict__ ws,
                                              unsigned* __restrict__ wq) {
    const int w = threadIdx.x >> 6, lane = threadIdx.x & 63;
    const int l = blockIdx.x * AWPB + w;
    const int i = l / SHEET, j = l % SHEET;
    const int xbase = i * IN_HW + j;

    // issue all 18 weight-stream loads up front (max memory-level parallelism)
    const float* rrow = rfs  + (size_t)l * F_AFF;
    const float* wrow = latw + (size_t)l * F_LAT;
    float rv[8], wv[10];
    #pragma unroll
    for (int it = 0; it < 8; ++it) {
        int f = it * 64 + lane;
        rv[it] = rrow[(f < F_AFF) ? f : 0];
    }
    #pragma unroll
    for (int it = 0; it < 10; ++it) {
        int f = it * 64 + lane;
        wv[it] = wrow[(f < F_LAT) ? f : 0];
    }

    // afferent dot
    const float2* atab = (const float2*)(ws + WS_AFFTAB);
    float dot = 0.f, rsum = 0.f;
    #pragma unroll
    for (int it = 0; it < 8; ++it) {
        int f = it * 64 + lane;
        float2 tb = atab[f];
        float r = (f < F_AFF) ? rv[it] : 0.f;
        float xv = x[xbase + __float_as_int(tb.y)];
        dot = fmaf(xv * tb.x, r, dot);
        rsum += r;
    }
    dot = wred(dot);
    rsum = wred(rsum);
    if (lane == 0) {
        float a = dot / rsum;
        out_rawaff[l] = 45.0f * a;                 // raw_aff
        float aff = a - ada[l];
        ws[WS_AFF + l] = aff;
        ws[WS_B0  + l] = fmaxf(aff, 0.f);          // lat_0 = relu(aff)
        ws[WS_LM  + l] = 0.f;
    }

    // lateral pack: bf16(w*lri/sum), pair layout (f, f+320)
    const float2* ltab = (const float2*)(ws + WS_LATTAB);
    float tmp[10], wsum = 0.f;
    #pragma unroll
    for (int it = 0; it < 10; ++it) {
        int f = it * 64 + lane;
        float lri = ltab[f].x;                     // 0 for f >= 625
        float v = (f < F_LAT) ? wv[it] : 0.f;
        wsum += v;
        tmp[it] = v * lri;
    }
    wsum = wred(wsum);
    const float inv = 1.0f / wsum;

    unsigned* dst = wq + (size_t)l * 320;
    #pragma unroll
    for (int k = 0; k < 5; ++k) {
        unsigned lo = f2bf(tmp[k]     * inv);
        unsigned hi = f2bf(tmp[k + 5] * inv);
        dst[k * 64 + lane] = lo | (hi << 16);
    }
}

// ---------------- lateral iteration: 5x10 tile, grid 512 = 2 blocks/CU ----------------
__global__ __launch_bounds__(BLK, 4) void k_lat(const unsigned* __restrict__ wq,
                                                float* __restrict__ ws,
                                                const float* __restrict__ lsrc,
                                                float* __restrict__ lat_out) {
    __shared__ float Lt[LT_N + 8];
    __shared__ float Ep[EP_N];
    const int b  = blockIdx.x;
    const int i0 = (b / TCOLS) * BH;
    const int j0 = (b % TCOLS) * BW;
    const int tid = threadIdx.x;
    const int w = tid >> 6, lane = tid & 63;
    const int lrow = (i0 + w) * SHEET + j0;        // wave w owns locs lrow+0..9

    // gather-offset table (per-lane registers)
    const float2* tab = (const float2*)(ws + WS_LATTAB);
    int off_reg[10];
    #pragma unroll
    for (int it = 0; it < 10; ++it) off_reg[it] = __float_as_int(tab[it * 64 + lane].y);

    // prefetch batch A: locs 0..4 packed weights (hidden under stage+conv)
    unsigned wpA[5][5];
    #pragma unroll
    for (int s = 0; s < 5; ++s) {
        const unsigned* row = wq + (size_t)(lrow + s) * 320;
        #pragma unroll
        for (int k = 0; k < 5; ++k) wpA[s][k] = row[k * 64 + lane];
    }

    // sre in registers (uniform)
    float sreg[25];
    #pragma unroll
    for (int q = 0; q < 25; ++q) sreg[q] = ws[WS_SRE + q];

    // ---- stage L tile (pad = HOMEO), 57 rows x 62 cols (width padded to 63) ----
    for (int idx = tid; idx < LT_N; idx += BLK) {
        int r = idx / LW, c = idx - r * LW;
        int y  = i0 + r - 26;
        int xx = j0 + c - 26;
        float v = HOMEO;
        if (c < 62 && (unsigned)y < SHEET && (unsigned)xx < SHEET) v = lsrc[y*SHEET + xx];
        Lt[idx] = v;
    }
    __syncthreads();

    // ---- 5x5 conv -> E field 53x58 (4-wide register blocked, parity-split store) ----
    for (int qi = tid; qi < EH * 15; qi += BLK) {
        int y = qi / 15, q = qi - y * 15;
        int x0 = q * 4;
        float a0 = 0.f, a1 = 0.f, a2 = 0.f, a3 = 0.f;
        #pragma unroll
        for (int u = 0; u < 5; ++u) {
            const float* row = &Lt[(y + u) * LW + x0];
            float ra[8];
            #pragma unroll
            for (int v = 0; v < 8; ++v) ra[v] = row[v];
            #pragma unroll
            for (int v = 0; v < 5; ++v) {
                float s = sreg[u * 5 + v];
                a0 = fmaf(ra[v],     s, a0);
                a1 = fmaf(ra[v + 1], s, a1);
                a2 = fmaf(ra[v + 2], s, a2);
                a3 = fmaf(ra[v + 3], s, a3);
            }
        }
        int yg = i0 - 24 + y;
        bool yok = (unsigned)yg < SHEET;
        int xg = j0 - 24 + x0;
        float v0 = (yok && (unsigned)(xg    ) < SHEET) ? a0 : HOMEO;
        float v1 = (yok && (unsigned)(xg + 1) < SHEET) ? a1 : HOMEO;
        float v2 = (yok && (unsigned)(xg + 2) < SHEET) ? a2 : HOMEO;
        float v3 = (yok && (unsigned)(xg + 3) < SHEET) ? a3 : HOMEO;
        int c0 = y * EWH + 2 * q;
        Ep[c0]               = v0;   // cols 58/59 of the 60-wide quad row land
        Ep[EP_HALF + c0]     = v1;   // in the per-row pad slot (col 29) - harmless
        Ep[c0 + 1]           = v2;
        Ep[EP_HALF + c0 + 1] = v3;
    }
    __syncthreads();

    // prefetch batch B: locs 5..9 (issued now, consumed after 5 dots -> latency hidden)
    unsigned wpB[5][5];
    #pragma unroll
    for (int s = 0; s < 5; ++s) {
        const unsigned* row = wq + (size_t)(lrow + 5 + s) * 320;
        #pragma unroll
        for (int k = 0; k < 5; ++k) wpB[s][k] = row[k * 64 + lane];
    }

    // ---- per-location 625-dot from register-resident bf16 weights ----
    #pragma unroll
    for (int s = 0; s < 10; ++s) {
        const int cc = s;
        const int gbase = (cc & 1) * EP_HALF + w * EWH + (cc >> 1);
        float acc = 0.f;
        #pragma unroll
        for (int k = 0; k < 5; ++k) {
            unsigned p = (s < 5) ? wpA[s][k] : wpB[s - 5][k];
            float e0 = Ep[gbase + off_reg[k]];
            float e1 = Ep[gbase + off_reg[k + 5]];
            acc = fmaf(e0, __uint_as_float(p << 16),         acc);
            acc = fmaf(e1, __uint_as_float(p & 0xffff0000u), acc);
        }
        acc = wred(acc);
        if (lane == 0) {
            int l = lrow + s;
            float ec = Ep[gbase + 24*EWH + 12];
            float v = ec * 0.45f - acc * 0.55f + ws[WS_AFF + l];
            v = tanhf(fmaxf(v, 0.f));
            lat_out[l] = v;
            ws[WS_LM + l] += v;
        }
    }
}

// ---------------- hebbian correlation: same 5x10 tiling, no conv ----------------
__global__ __launch_bounds__(BLK, 4) void k_hebb(const unsigned* __restrict__ wq,
                                                 float* __restrict__ ws) {
    __shared__ float LMp[EP_N];
    __shared__ float part[5];
    const int b  = blockIdx.x;
    const int i0 = (b / TCOLS) * BH;
    const int j0 = (b % TCOLS) * BW;
    const int tid = threadIdx.x;
    const int w = tid >> 6, lane = tid & 63;
    const int lrow = (i0 + w) * SHEET + j0;
    const float* lm = ws + WS_LM;

    const float2* tab = (const float2*)(ws + WS_LATTAB);
    int off_reg[10];
    #pragma unroll
    for (int it = 0; it < 10; ++it) off_reg[it] = __float_as_int(tab[it * 64 + lane].y);

    unsigned wpA[5][5], wpB[5][5];
    #pragma unroll
    for (int s = 0; s < 5; ++s) {
        const unsigned* rowA = wq + (size_t)(lrow + s) * 320;
        const unsigned* rowB = wq + (size_t)(lrow + 5 + s) * 320;
        #pragma unroll
        for (int k = 0; k < 5; ++k) { wpA[s][k] = rowA[k * 64 + lane]; wpB[s][k] = rowB[k * 64 + lane]; }
    }

    // stage lat_mean tile (x0.1, pad HOMEO), parity-split 53x58
    for (int idx = tid; idx < EP_N; idx += BLK) {
        int p   = idx / EP_HALF;
        int rem = idx - p * EP_HALF;
        int y   = rem / EWH;
        int col = rem - y * EWH;
        int yg = i0 - 24 + y;
        int xg = j0 - 24 + 2 * col + p;
        float v = HOMEO;
        if ((unsigned)yg < SHEET && (unsigned)xg < SHEET && col < 29) v = lm[yg*SHEET + xg] * 0.1f;
        LMp[idx] = v;
    }
    __syncthreads();

    float wacc = 0.f;
    #pragma unroll
    for (int s = 0; s < 10; ++s) {
        const int cc = s;
        const int gbase = (cc & 1) * EP_HALF + w * EWH + (cc >> 1);
        float acc = 0.f;
        #pragma unroll
        for (int k = 0; k < 5; ++k) {
            unsigned p = (s < 5) ? wpA[s][k] : wpB[s - 5][k];
            float e0 = LMp[gbase + off_reg[k]];
            float e1 = LMp[gbase + off_reg[k + 5]];
            acc = fmaf(e0, __uint_as_float(p << 16),         acc);
            acc = fmaf(e1, __uint_as_float(p & 0xffff0000u), acc);
        }
        acc = wred(acc);
        if (lane == 0) {
            float lmv = LMp[gbase + 24*EWH + 12];      // lat_mean[l] * 0.1
            wacc += lmv * 62.5f * acc;
        }
    }
    if (lane == 0) part[w] = wacc;
    __syncthreads();
    if (tid == 0) {
        float s = 0.f;
        #pragma unroll
        for (int q = 0; q < 5; ++q) s += part[q];
        ws[WS_PART + b] = s;
    }
}

// ---------------- deterministic final reduce ----------------
__global__ __launch_bounds__(512) void k_final(const float* __restrict__ ws,
                                               float* __restrict__ out_scalar) {
    __shared__ float red[512];
    red[threadIdx.x] = ws[WS_PART + threadIdx.x];
    __syncthreads();
    #pragma unroll
    for (int st = 256; st > 0; st >>= 1) {
        if (threadIdx.x < st) red[threadIdx.x] += red[threadIdx.x + st];
        __syncthreads();
    }
    if (threadIdx.x == 0) *out_scalar = red[0];
}

extern "C" void kernel_launch(void* const* d_in, const int* in_sizes, int n_in,
                              void* d_out, int out_size, void* d_ws, size_t ws_size,
                              hipStream_t stream) {
    const float* x    = (const float*)d_in[0];
    const float* rfs  = (const float*)d_in[1];
    const float* latw = (const float*)d_in[2];
    const float* ada  = (const float*)d_in[3];
    float* out = (float*)d_out;
    float* ws  = (float*)d_ws;
    unsigned* wq = (unsigned*)(ws + WS_WQ);

    k_init<<<1, 1024, 0, stream>>>(ws);
    k_pre<<<ANBLK, ABLK, 0, stream>>>(x, rfs, latw, ada, out, ws, wq);

    for (int t = 0; t < N_ITERS; ++t) {
        const float* src = ws + ((t & 1) ? WS_B1 : WS_B0);
        float* dst = (t == N_ITERS - 1) ? (out + LTOT)
                                        : (ws + ((t & 1) ? WS_B0 : WS_B1));
        k_lat<<<GRID_L, BLK, 0, stream>>>(wq, ws, src, dst);
    }

    k_hebb<<<GRID_L, BLK, 0, stream>>>(wq, ws);
    k_final<<<1, 512, 0, stream>>>(ws, out + 2 * LTOT);
}